// Round 3
// baseline (1477.441 us; speedup 1.0000x reference)
//
#include <hip/hip_runtime.h>

typedef unsigned short u16;
typedef unsigned int   u32;
typedef unsigned long long u64;
typedef __attribute__((ext_vector_type(8))) short s8v;   // 8 x bf16 bits (4 VGPRs)
typedef __attribute__((ext_vector_type(4))) float f4v;   // MFMA accumulator
typedef __attribute__((ext_vector_type(4))) int   i4v;   // 4 VGPRs (generic 16B)
typedef __attribute__((ext_vector_type(2))) unsigned int u32x2;

#define B_SZ  64
#define T_LEN 512
#define U_DIM 256
#define E_DIM 300
#define EP    320          // E padded to multiple of 32
#define G3    768          // 3*U
#define NTOT  1536         // both directions concatenated
#define C_DIM 20
#define BT    (B_SZ*T_LEN)

__device__ __forceinline__ float bf2f(u16 h){ return __uint_as_float(((u32)h)<<16); }
__device__ __forceinline__ u16 f2bf(float f){
  u32 u = __float_as_uint(f);
  u32 r = (u + 0x7FFFu + ((u>>16)&1u)) >> 16;   // RNE
  return (u16)r;
}

// ------------- embedding gather f32 -> bf16, K-pad (300 -> 320, zeros) --------
__global__ void embed_pad(const int* __restrict__ x, const float* __restrict__ emb,
                          u16* __restrict__ e){
  int idx = blockIdx.x*256 + threadIdx.x;
  if(idx >= BT*EP) return;
  int row = idx / EP, col = idx - row*EP;
  u16 v = 0;
  if(col < E_DIM) v = f2bf(emb[(size_t)x[row]*E_DIM + col]);
  e[idx] = v;
}

// ------ transpose + concat two f32 [K,768] sources -> bf16 dst[N][Kp] ---------
__global__ void transpose_cc(const float* __restrict__ A, const float* __restrict__ Bm,
                             u16* __restrict__ dst, int K, int Kp, int N){
  int idx = blockIdx.x*256 + threadIdx.x;
  if(idx >= N*Kp) return;
  int n = idx / Kp, k = idx - n*Kp;
  u16 v = 0;
  if(k < K){
    const float* s = (n < G3) ? A : Bm;
    int nn = (n < G3) ? n : n - G3;
    v = f2bf(s[(size_t)k*G3 + nn]);
  }
  dst[idx] = v;
}

// ------- GEMM: packed preacts for the M=4 scan -------------------------------
// xq layout (u16): [dir][t][b][g][lc16][ut16]; total 2*512*64*3*256 u16.
// acc[i][j][r]: row = wm*64+i*16+quad*4+r = t_loc*4+b_loc -> t = tb0+wm*16+i*4+quad,
// b = b0r + r. 4 consecutive ut (= j) for one (b,t,g,lc) pack into one u64 store.
// Recurrent bias b[1] for gates z,r (g<2) is folded in here (saves scan VALU).
__global__ __launch_bounds__(256) void gemm_bt(
    const u16* __restrict__ A, const u16* __restrict__ BT_, u16* __restrict__ Cq,
    int Kp, const float* __restrict__ biasA, const float* __restrict__ biasB)
{
  __shared__ u16 Al[128][40];   // +8 pad breaks bank collisions
  __shared__ u16 Bl[128][40];
  int tid = threadIdx.x;
  int w = tid>>6, l = tid&63, lc = l&15, quad = l>>4;
  int wm = w>>1, wn = w&1;
  int nb = blockIdx.x*128;
  int bg4 = blockIdx.y >> 4, tg = blockIdx.y & 15;
  int b0r = bg4*4, tb0 = tg*32;

  f4v acc[4][4];
  #pragma unroll
  for(int i=0;i<4;i++)
    #pragma unroll
    for(int j=0;j<4;j++) acc[i][j] = (f4v){0.f,0.f,0.f,0.f};

  int nk = Kp >> 5;
  for(int kt=0; kt<nk; kt++){
    __syncthreads();
    {
      int c0 = tid, c1 = tid + 256;
      int r0 = c0>>2, k80 = c0&3;
      int r1 = c1>>2, k81 = c1&3;
      size_t ga0 = ((size_t)(b0r + (r0&3))*T_LEN + tb0 + (r0>>2))*Kp;
      size_t ga1 = ((size_t)(b0r + (r1&3))*T_LEN + tb0 + (r1>>2))*Kp;
      *(s8v*)&Al[r0][k80*8] = *(const s8v*)(A + ga0 + kt*32 + k80*8);
      *(s8v*)&Al[r1][k81*8] = *(const s8v*)(A + ga1 + kt*32 + k81*8);
      *(s8v*)&Bl[r0][k80*8] = *(const s8v*)(BT_ + (size_t)(nb+r0)*Kp + kt*32 + k80*8);
      *(s8v*)&Bl[r1][k81*8] = *(const s8v*)(BT_ + (size_t)(nb+r1)*Kp + kt*32 + k81*8);
    }
    __syncthreads();
    s8v af[4], bf[4];
    #pragma unroll
    for(int i=0;i<4;i++) af[i] = *(const s8v*)&Al[wm*64 + i*16 + lc][quad*8];
    #pragma unroll
    for(int j=0;j<4;j++) bf[j] = *(const s8v*)&Bl[wn*64 + j*16 + lc][quad*8];
    #pragma unroll
    for(int i=0;i<4;i++)
      #pragma unroll
      for(int j=0;j<4;j++)
        acc[i][j] = __builtin_amdgcn_mfma_f32_16x16x32_bf16(af[i], bf[j], acc[i][j],0,0,0);
  }

  // packed epilogue -> xq[dir][t][b][g][lc][ut], one u64 (4 ut) per (i,r)
  int dirq = (nb >= G3) ? 1 : 0;
  int c7b  = nb - dirq*G3 + wn*64;      // col within dir, minus lc and j*16
  int g    = c7b >> 8;
  int ut0  = (c7b >> 4) & 15;
  const float* bb = dirq ? biasB : biasA;
  float bj[4];
  #pragma unroll
  for(int j=0;j<4;j++){
    int cc = c7b + j*16 + lc;
    bj[j] = bb[cc] + ((g < 2) ? bb[G3 + cc] : 0.f);   // fold b[1] for z,r gates
  }
  #pragma unroll
  for(int i=0;i<4;i++){
    int t = tb0 + wm*16 + i*4 + quad;
    size_t base = ((((size_t)dirq*T_LEN + t)*B_SZ + b0r)*3 + g)*256 + lc*16 + ut0;
    #pragma unroll
    for(int r=0;r<4;r++){
      u16 p0 = f2bf(acc[i][0][r] + bj[0]);
      u16 p1 = f2bf(acc[i][1][r] + bj[1]);
      u16 p2 = f2bf(acc[i][2][r] + bj[2]);
      u16 p3 = f2bf(acc[i][3][r] + bj[3]);
      *(u64*)(Cq + base + (size_t)r*768) =
        (u64)p0 | ((u64)p1<<16) | ((u64)p2<<32) | ((u64)p3<<48);
    }
  }
}

// ---------------- GRU scan: fully register-resident recurrent weights --------
// 32 blocks (dir x 16 batch-groups of 4) x 256 threads (4 waves, 1 wave/SIMD).
// Per wave: 192 N-cols (u in [w*64,w*64+64), 3 gates) x K=256 -> 96 B-frags:
//   64 (gates z,r) in AGPR a0..a255, 32 (gate h) in VGPRs bv[32].
// Step is phase-split (ut01 / ut23): gates of phase A interleave into phase-B
// MFMA issue gaps (one wave/SIMD -> ~18 free issue slots per MFMA).

#define ACLB \
 "a0","a1","a2","a3","a4","a5","a6","a7","a8","a9","a10","a11","a12","a13","a14","a15", \
 "a16","a17","a18","a19","a20","a21","a22","a23","a24","a25","a26","a27","a28","a29","a30","a31", \
 "a32","a33","a34","a35","a36","a37","a38","a39","a40","a41","a42","a43","a44","a45","a46","a47", \
 "a48","a49","a50","a51","a52","a53","a54","a55","a56","a57","a58","a59","a60","a61","a62","a63", \
 "a64","a65","a66","a67","a68","a69","a70","a71","a72","a73","a74","a75","a76","a77","a78","a79", \
 "a80","a81","a82","a83","a84","a85","a86","a87","a88","a89","a90","a91","a92","a93","a94","a95", \
 "a96","a97","a98","a99","a100","a101","a102","a103","a104","a105","a106","a107","a108","a109","a110","a111", \
 "a112","a113","a114","a115","a116","a117","a118","a119","a120","a121","a122","a123","a124","a125","a126","a127", \
 "a128","a129","a130","a131","a132","a133","a134","a135","a136","a137","a138","a139","a140","a141","a142","a143", \
 "a144","a145","a146","a147","a148","a149","a150","a151","a152","a153","a154","a155","a156","a157","a158","a159", \
 "a160","a161","a162","a163","a164","a165","a166","a167","a168","a169","a170","a171","a172","a173","a174","a175", \
 "a176","a177","a178","a179","a180","a181","a182","a183","a184","a185","a186","a187","a188","a189","a190","a191", \
 "a192","a193","a194","a195","a196","a197","a198","a199","a200","a201","a202","a203","a204","a205","a206","a207", \
 "a208","a209","a210","a211","a212","a213","a214","a215","a216","a217","a218","a219","a220","a221","a222","a223", \
 "a224","a225","a226","a227","a228","a229","a230","a231","a232","a233","a234","a235","a236","a237","a238","a239", \
 "a240","a241","a242","a243","a244","a245","a246","a247","a248","a249","a250","a251","a252","a253","a254","a255"

#define AFENCE asm volatile("" ::: ACLB)

#define BINIT(NT,KT,A0,A1,A2,A3) { \
  i4v t = *(const i4v*)(rkd + (size_t)((((NT)>>2)<<8) + w*64 + (((NT)&3)<<4) + lc)*U_DIM \
                            + (KT)*32 + quad*8); \
  asm volatile("v_accvgpr_write_b32 a" #A0 ", %0\n\t" \
               "v_accvgpr_write_b32 a" #A1 ", %1\n\t" \
               "v_accvgpr_write_b32 a" #A2 ", %2\n\t" \
               "v_accvgpr_write_b32 a" #A3 ", %3" \
               :: "v"(t[0]), "v"(t[1]), "v"(t[2]), "v"(t[3]) : ACLB); }

#define MFZ(ACC,AF,BF) \
  asm("v_mfma_f32_16x16x32_bf16 %0, %1, %2, 0" : "=&v"(ACC) : "v"(AF), "v"(BF))
#define MFV(ACC,AF,BF) \
  asm("v_mfma_f32_16x16x32_bf16 %0, %1, %2, %0" : "+v"(ACC) : "v"(AF), "v"(BF))
#define MFZA(ACC,AF,AR) \
  asm("v_mfma_f32_16x16x32_bf16 %0, %1, " AR ", 0" : "=&v"(ACC) : "v"(AF))
#define MFAA(ACC,AF,AR) \
  asm("v_mfma_f32_16x16x32_bf16 %0, %1, " AR ", %0" : "+v"(ACC) : "v"(AF))

// phase A: accs {0,1,4,5,8,9} = ut 0,1 for z,r,h
#define KA0() { \
  MFZA(acc[0],af[0],"a[0:3]");   MFZA(acc[1],af[0],"a[4:7]"); \
  MFZA(acc[4],af[0],"a[16:19]"); MFZA(acc[5],af[0],"a[20:23]"); \
  MFZ(acc[8],af[0],bv[0]); MFZ(acc[9],af[0],bv[1]); }
#define KA(KT,Z0,Z1,R0,R1) { \
  MFAA(acc[0],af[KT],Z0); MFAA(acc[1],af[KT],Z1); \
  MFAA(acc[4],af[KT],R0); MFAA(acc[5],af[KT],R1); \
  MFV(acc[8],af[KT],bv[(KT)*4+0]); MFV(acc[9],af[KT],bv[(KT)*4+1]); }

// phase B: accs {2,3,6,7,10,11} = ut 2,3 for z,r,h
#define KB0() { \
  MFZA(acc[2],af[0],"a[8:11]");  MFZA(acc[3],af[0],"a[12:15]"); \
  MFZA(acc[6],af[0],"a[24:27]"); MFZA(acc[7],af[0],"a[28:31]"); \
  MFZ(acc[10],af[0],bv[2]); MFZ(acc[11],af[0],bv[3]); }
#define KB(KT,Z2,Z3,R2,R3) { \
  MFAA(acc[2],af[KT],Z2); MFAA(acc[3],af[KT],Z3); \
  MFAA(acc[6],af[KT],R2); MFAA(acc[7],af[KT],R3); \
  MFV(acc[10],af[KT],bv[(KT)*4+2]); MFV(acc[11],af[KT],bv[(KT)*4+3]); }

// MFMA->VALU hazard fences (16 nop cycles), per phase
#define FENCEA asm volatile("s_nop 7\n\ts_nop 7" \
  : "+v"(acc[0]),"+v"(acc[1]),"+v"(acc[4]),"+v"(acc[5]), \
    "+v"(acc[8]),"+v"(acc[9]) :: ACLB)
#define FENCEB asm volatile("s_nop 7\n\ts_nop 7" \
  : "+v"(acc[2]),"+v"(acc[3]),"+v"(acc[6]),"+v"(acc[7]), \
    "+v"(acc[10]),"+v"(acc[11]) :: ACLB)

#define LBAR asm volatile("s_waitcnt lgkmcnt(0)\n\ts_barrier" ::: ACLB, "memory")

__device__ __forceinline__ float bsel(u32x2 v, int i){
  u32 wv = (i & 2) ? (u32)v[1] : (u32)v[0];
  return __uint_as_float((i & 1) ? (wv & 0xffff0000u) : (wv << 16));
}

// gate + state update for one ut (cell = acc[.][0]; batch = quad)
#define GATE(UT) { \
  float xz = bsel(cz, UT); \
  float xr = bsel(cr, UT); \
  float xh = bsel(ch, UT); \
  float zf = acc[UT][0]   + xz; \
  float rf = acc[4+UT][0] + xr; \
  float rh = acc[8+UT][0] + b1h[UT]; \
  zf = __builtin_amdgcn_rcpf(1.f + __expf(-zf)); \
  rf = __builtin_amdgcn_rcpf(1.f + __expf(-rf)); \
  float hc = xh + rf*rh; \
  float e2 = __expf(2.f*hc); \
  float th = 1.f - 2.f*__builtin_amdgcn_rcpf(e2 + 1.f); \
  float hn = th + zf*(hpc[UT] - th); \
  hpc[UT] = hn; \
  u16 hbf = f2bf(hn); \
  hb[nxt][quad*4][w*64 + (UT)*16 + lc] = hbf; \
  if(MODE == 0) \
    hp[(UT)*16] = hbf; \
  else if(step == T_LEN-1) \
    h2out[(size_t)(b0+quad)*(2*U_DIM) + dir*U_DIM + w*64 + (UT)*16 + lc] = hn; \
}

template<int MODE>
__global__ __launch_bounds__(256,1) void gru_scan3(
    const u16* __restrict__ xq,    // packed preacts (see gemm_bt)
    const u16* __restrict__ rkT,   // [2][768][256] bf16 transposed recurrent kernels
    const float* __restrict__ bF, const float* __restrict__ bB,  // b[2][768] f32
    u16* __restrict__ h1out,       // MODE 0: [BT,512]
    float* __restrict__ h2out)     // MODE 1: [64,512] final states
{
  int dir = blockIdx.x & 1, bg = blockIdx.x >> 1;
  int b0 = bg*4;
  int tid = threadIdx.x;
  int w = tid>>6, l = tid&63, lc = l&15, quad = l>>4;

  __shared__ u16 hb[2][16][264];   // double-buffered h, rows {0,4,8,12} real
  for(int i=tid; i<2*16*264; i+=256) ((u16*)hb)[i] = 0;

  const u16* rkd = rkT + (size_t)dir*G3*U_DIM;

  // h-gate B-frags in VGPRs (32 frags)
  s8v bv[32];
  #pragma unroll
  for(int kt=0;kt<8;kt++)
    #pragma unroll
    for(int ut=0;ut<4;ut++)
      bv[kt*4+ut] = *(const s8v*)(rkd + (size_t)(512 + w*64 + ut*16 + lc)*U_DIM
                                      + kt*32 + quad*8);

  // z,r-gate B-frags in AGPRs: a[(KT*32 + NT*4) .. +3], NT = g*4+ut (g in {0,1})
  BINIT(0,0,0,1,2,3)       BINIT(1,0,4,5,6,7)       BINIT(2,0,8,9,10,11)      BINIT(3,0,12,13,14,15)
  BINIT(4,0,16,17,18,19)   BINIT(5,0,20,21,22,23)   BINIT(6,0,24,25,26,27)    BINIT(7,0,28,29,30,31)
  BINIT(0,1,32,33,34,35)   BINIT(1,1,36,37,38,39)   BINIT(2,1,40,41,42,43)    BINIT(3,1,44,45,46,47)
  BINIT(4,1,48,49,50,51)   BINIT(5,1,52,53,54,55)   BINIT(6,1,56,57,58,59)    BINIT(7,1,60,61,62,63)
  BINIT(0,2,64,65,66,67)   BINIT(1,2,68,69,70,71)   BINIT(2,2,72,73,74,75)    BINIT(3,2,76,77,78,79)
  BINIT(4,2,80,81,82,83)   BINIT(5,2,84,85,86,87)   BINIT(6,2,88,89,90,91)    BINIT(7,2,92,93,94,95)
  BINIT(0,3,96,97,98,99)   BINIT(1,3,100,101,102,103) BINIT(2,3,104,105,106,107) BINIT(3,3,108,109,110,111)
  BINIT(4,3,112,113,114,115) BINIT(5,3,116,117,118,119) BINIT(6,3,120,121,122,123) BINIT(7,3,124,125,126,127)
  BINIT(0,4,128,129,130,131) BINIT(1,4,132,133,134,135) BINIT(2,4,136,137,138,139) BINIT(3,4,140,141,142,143)
  BINIT(4,4,144,145,146,147) BINIT(5,4,148,149,150,151) BINIT(6,4,152,153,154,155) BINIT(7,4,156,157,158,159)
  BINIT(0,5,160,161,162,163) BINIT(1,5,164,165,166,167) BINIT(2,5,168,169,170,171) BINIT(3,5,172,173,174,175)
  BINIT(4,5,176,177,178,179) BINIT(5,5,180,181,182,183) BINIT(6,5,184,185,186,187) BINIT(7,5,188,189,190,191)
  BINIT(0,6,192,193,194,195) BINIT(1,6,196,197,198,199) BINIT(2,6,200,201,202,203) BINIT(3,6,204,205,206,207)
  BINIT(4,6,208,209,210,211) BINIT(5,6,212,213,214,215) BINIT(6,6,216,217,218,219) BINIT(7,6,220,221,222,223)
  BINIT(0,7,224,225,226,227) BINIT(1,7,228,229,230,231) BINIT(2,7,232,233,234,235) BINIT(3,7,236,237,238,239)
  BINIT(4,7,240,241,242,243) BINIT(5,7,244,245,246,247) BINIT(6,7,248,249,250,251) BINIT(7,7,252,253,254,255)

  // recurrent bias for h-gate only (z,r folded into gemm bias)
  float b1h[4];
  const float* bias1 = (dir ? bB : bF) + G3;
  #pragma unroll
  for(int ut=0; ut<4; ut++) b1h[ut] = bias1[2*U_DIM + w*64 + ut*16 + lc];

  int t0 = dir ? (T_LEN-1) : 0;
  long qstride = dir ? -(long)(64*3*256) : (long)(64*3*256);
  const u16* xp = xq + ((((size_t)dir*T_LEN + t0)*B_SZ + (b0+quad))*3)*256 + lc*16 + w*4;
  long hstride = dir ? -(long)(2*U_DIM) : (long)(2*U_DIM);
  u16* hp = (MODE==0)
    ? (h1out + ((size_t)(b0+quad)*T_LEN + t0)*(2*U_DIM) + dir*U_DIM + w*64 + lc)
    : nullptr;

  float hpc[4] = {0.f, 0.f, 0.f, 0.f};   // carried h (own cells), f32

  __syncthreads();

  int cur = 0;
  for(int step=0; step<T_LEN; step++){
    AFENCE;
    int nxt = cur ^ 1;

    // packed xw preacts: 3 x 8B (4 ut cells each), hidden under the MFMA phase
    u32x2 cz = *(const u32x2*)(xp);
    u32x2 cr = *(const u32x2*)(xp + 256);
    u32x2 ch = *(const u32x2*)(xp + 512);

    // all 8 A-frags upfront: no hb[cur] reads remain after this point, so
    // phase-A gates may write hb[nxt] while phase-B MFMAs still run
    s8v af[8];
    #pragma unroll
    for(int kt=0;kt<8;kt++) af[kt] = *(const s8v*)&hb[cur][lc][kt*32 + quad*8];

    f4v acc[12];   // [g*4+ut]; cell value in reg 0 (batch = quad at row quad*4)

    // phase A (ut 0,1): 48 MFMAs
    KA0();
    KA(1,"a[32:35]","a[36:39]","a[48:51]","a[52:55]")
    KA(2,"a[64:67]","a[68:71]","a[80:83]","a[84:87]")
    KA(3,"a[96:99]","a[100:103]","a[112:115]","a[116:119]")
    KA(4,"a[128:131]","a[132:135]","a[144:147]","a[148:151]")
    KA(5,"a[160:163]","a[164:167]","a[176:179]","a[180:183]")
    KA(6,"a[192:195]","a[196:199]","a[208:211]","a[212:215]")
    KA(7,"a[224:227]","a[228:231]","a[240:243]","a[244:247]")

    // phase B starts; A-gates interleave into its issue gaps
    KB0();
    KB(1,"a[40:43]","a[44:47]","a[56:59]","a[60:63]")
    FENCEA;
    GATE(0)
    KB(2,"a[72:75]","a[76:79]","a[88:91]","a[92:95]")
    KB(3,"a[104:107]","a[108:111]","a[120:123]","a[124:127]")
    GATE(1)
    KB(4,"a[136:139]","a[140:143]","a[152:155]","a[156:159]")
    KB(5,"a[168:171]","a[172:175]","a[184:187]","a[188:191]")
    KB(6,"a[200:203]","a[204:207]","a[216:219]","a[220:223]")
    KB(7,"a[232:235]","a[236:239]","a[248:251]","a[252:255]")
    FENCEB;
    GATE(2)
    GATE(3)

    xp += qstride;
    if(MODE==0) hp += hstride;
    LBAR;
    cur ^= 1;
  }
}

// ---------------- final projection + softmax (f32 output) ---------------------
__global__ void out_softmax(const float* __restrict__ h2, const float* __restrict__ wout,
                            const float* __restrict__ bout, float* __restrict__ out)
{
  __shared__ float lg[C_DIM];
  int b = blockIdx.x, l = threadIdx.x;   // 64 threads = 1 wave
  float acc[C_DIM];
  #pragma unroll
  for(int c=0;c<C_DIM;c++) acc[c] = 0.f;
  for(int k=l; k<2*U_DIM; k+=64){
    float hv = h2[b*2*U_DIM + k];
    #pragma unroll
    for(int c=0;c<C_DIM;c++) acc[c] += hv * wout[k*C_DIM + c];
  }
  #pragma unroll
  for(int c=0;c<C_DIM;c++){
    float v = acc[c];
    for(int off=32; off; off>>=1) v += __shfl_down(v, off);
    if(l==0) lg[c] = v + bout[c];
  }
  __syncthreads();
  if(l==0){
    float mx = lg[0];
    for(int c=1;c<C_DIM;c++) mx = fmaxf(mx, lg[c]);
    float sum = 0.f, ex[C_DIM];
    for(int c=0;c<C_DIM;c++){ ex[c] = __expf(lg[c]-mx); sum += ex[c]; }
    for(int c=0;c<C_DIM;c++) out[b*C_DIM + c] = ex[c]/sum;
  }
}

extern "C" void kernel_launch(void* const* d_in, const int* in_sizes, int n_in,
                              void* d_out, int out_size, void* d_ws, size_t ws_size,
                              hipStream_t stream)
{
  const int*   x    = (const int*)d_in[0];
  const float* emb  = (const float*)d_in[1];
  const float* k1f  = (const float*)d_in[2];
  const float* rk1f = (const float*)d_in[3];
  const float* b1f  = (const float*)d_in[4];
  const float* k1b  = (const float*)d_in[5];
  const float* rk1b = (const float*)d_in[6];
  const float* b1b  = (const float*)d_in[7];
  const float* k2f  = (const float*)d_in[8];
  const float* rk2f = (const float*)d_in[9];
  const float* b2f  = (const float*)d_in[10];
  const float* k2b  = (const float*)d_in[11];
  const float* rk2b = (const float*)d_in[12];
  const float* b2b  = (const float*)d_in[13];
  const float* wout = (const float*)d_in[14];
  const float* bout = (const float*)d_in[15];

  char* ws = (char*)d_ws;
  u16*  k1t   = (u16*)(ws);                       // 983,040 B     [1536,320]
  u16*  k2t   = (u16*)(ws + 983040);              // 1,572,864 B   [1536,512]
  u16*  rkt   = (u16*)(ws + 2555904);             // 1,572,864 B   4x[768,256]
  float* h2   = (float*)(ws + 4128768);           // 131,072 B     [64,512]
  u16*  h1    = (u16*)(ws + 4259840);             // 33,554,432 B  [BT,512]
  u16*  e_pad = (u16*)(ws + 4259840);             // (alias h1)
  u16*  xq    = (u16*)(ws + 37814272);            // 100,663,296 B packed preacts

  transpose_cc<<<(NTOT*EP +255)/256,256,0,stream>>>(k1f, k1b, k1t, E_DIM, EP, NTOT);
  transpose_cc<<<(NTOT*512+255)/256,256,0,stream>>>(k2f, k2b, k2t, 512, 512, NTOT);
  transpose_cc<<<(G3*U_DIM+255)/256,256,0,stream>>>(rk1f, rk1f, rkt,                U_DIM, U_DIM, G3);
  transpose_cc<<<(G3*U_DIM+255)/256,256,0,stream>>>(rk1b, rk1b, rkt + 1*G3*U_DIM,   U_DIM, U_DIM, G3);
  transpose_cc<<<(G3*U_DIM+255)/256,256,0,stream>>>(rk2f, rk2f, rkt + 2*G3*U_DIM,   U_DIM, U_DIM, G3);
  transpose_cc<<<(G3*U_DIM+255)/256,256,0,stream>>>(rk2b, rk2b, rkt + 3*G3*U_DIM,   U_DIM, U_DIM, G3);

  embed_pad<<<(BT*EP)/256,256,0,stream>>>(x, emb, e_pad);

  // layer 1: xq = pack(e @ K1 + b0 [+ b1 for z,r]) ; scan -> h1
  gemm_bt<<<dim3(12,256),256,0,stream>>>(e_pad, k1t, xq, EP, b1f, b1b);
  gru_scan3<0><<<32,256,0,stream>>>(xq, rkt, b1f, b1b, h1, nullptr);

  // layer 2: xq = pack(h1 @ K2 + b0 [+ b1 for z,r]) ; scan -> h2 (final states)
  gemm_bt<<<dim3(12,256),256,0,stream>>>(h1, k2t, xq, 512, b2f, b2b);
  gru_scan3<1><<<32,256,0,stream>>>(xq, rkt + 2*G3*U_DIM, b2f, b2b, nullptr, h2);

  out_softmax<<<64,64,0,stream>>>(h2, wout, bout, (float*)d_out);
}

// Round 4
// 1228.969 us; speedup vs baseline: 1.2022x; 1.2022x over previous
//
#include <hip/hip_runtime.h>

typedef unsigned char  u8;
typedef unsigned short u16;
typedef unsigned int   u32;
typedef unsigned long long u64;
typedef __attribute__((ext_vector_type(8))) short s8v;   // 8 x bf16 bits (4 VGPRs)
typedef __attribute__((ext_vector_type(4))) float f4v;   // MFMA accumulator
typedef __attribute__((ext_vector_type(4))) int   i4v;   // 4 VGPRs (generic 16B)
typedef __attribute__((ext_vector_type(8))) int   i8v;   // 8 VGPRs (fp8 MFMA operand)
typedef __attribute__((ext_vector_type(2))) unsigned int u32x2;

#define B_SZ  64
#define T_LEN 512
#define U_DIM 256
#define E_DIM 300
#define EP    320          // E padded to multiple of 32
#define G3    768          // 3*U
#define NTOT  1536         // both directions concatenated
#define C_DIM 20
#define BT    (B_SZ*T_LEN)

__device__ __forceinline__ float bf2f(u16 h){ return __uint_as_float(((u32)h)<<16); }
__device__ __forceinline__ u16 f2bf(float f){
  u32 u = __float_as_uint(f);
  u32 r = (u + 0x7FFFu + ((u>>16)&1u)) >> 16;   // RNE
  return (u16)r;
}

// f32 -> OCP e4m3fn, RNE, handles subnormals + 448 clamp (prep kernels only)
__device__ __forceinline__ u8 f2fp8(float f){
  u32 u = __float_as_uint(f);
  u32 s = (u>>24)&0x80u;
  u32 au = u & 0x7fffffffu;
  if(au < 0x3C800000u){                       // |f| < 2^-6: subnormal range
    float m = rintf(__uint_as_float(au) * 512.f);   // 0..8 (RNE)
    return (u8)(s | (u32)(int)m);             // m==8 -> 0x08 == 2^-6 normal
  }
  int e = (int)(au>>23) - 127;
  u32 mant = au & 0x7fffffu;
  u32 lsb = (mant>>20)&1u;
  mant += 0x7FFFFu + lsb;                     // RNE to 3 mantissa bits
  if(mant >> 23){ mant = 0; e += 1; }
  if(e > 8 || (e==8 && ((mant>>20)&7u)==7u)) return (u8)(s | 0x7Eu);  // clamp 448
  return (u8)(s | ((u32)(e+7)<<3) | ((mant>>20)&7u));
}

// ------------- embedding gather f32 -> bf16, K-pad (300 -> 320, zeros) --------
__global__ void embed_pad(const int* __restrict__ x, const float* __restrict__ emb,
                          u16* __restrict__ e){
  int idx = blockIdx.x*256 + threadIdx.x;
  if(idx >= BT*EP) return;
  int row = idx / EP, col = idx - row*EP;
  u16 v = 0;
  if(col < E_DIM) v = f2bf(emb[(size_t)x[row]*E_DIM + col]);
  e[idx] = v;
}

// ------ transpose + concat two f32 [K,768] sources -> bf16 dst[N][Kp] ---------
__global__ void transpose_cc(const float* __restrict__ A, const float* __restrict__ Bm,
                             u16* __restrict__ dst, int K, int Kp, int N){
  int idx = blockIdx.x*256 + threadIdx.x;
  if(idx >= N*Kp) return;
  int n = idx / Kp, k = idx - n*Kp;
  u16 v = 0;
  if(k < K){
    const float* s = (n < G3) ? A : Bm;
    int nn = (n < G3) ? n : n - G3;
    v = f2bf(s[(size_t)k*G3 + nn]);
  }
  dst[idx] = v;
}

// ------ recurrent kernel f32 [256][768] -> fp8 e4m3 transposed [768][256] -----
__global__ void transpose_fp8(const float* __restrict__ rk, u8* __restrict__ dst){
  int idx = blockIdx.x*256 + threadIdx.x;     // 768*256
  if(idx >= G3*U_DIM) return;
  int n = idx >> 8, k = idx & 255;
  dst[idx] = f2fp8(rk[(size_t)k*G3 + n]);
}

// ------- GEMM: packed preacts for the M=4 scan -------------------------------
// xq layout (u16): [dir][t][b][g][lc16][ut16]; total 2*512*64*3*256 u16.
// Recurrent bias b[1] for gates z,r (g<2) is folded in here (saves scan VALU).
__global__ __launch_bounds__(256) void gemm_bt(
    const u16* __restrict__ A, const u16* __restrict__ BT_, u16* __restrict__ Cq,
    int Kp, const float* __restrict__ biasA, const float* __restrict__ biasB)
{
  __shared__ u16 Al[128][40];   // +8 pad breaks bank collisions
  __shared__ u16 Bl[128][40];
  int tid = threadIdx.x;
  int w = tid>>6, l = tid&63, lc = l&15, quad = l>>4;
  int wm = w>>1, wn = w&1;
  int nb = blockIdx.x*128;
  int bg4 = blockIdx.y >> 4, tg = blockIdx.y & 15;
  int b0r = bg4*4, tb0 = tg*32;

  f4v acc[4][4];
  #pragma unroll
  for(int i=0;i<4;i++)
    #pragma unroll
    for(int j=0;j<4;j++) acc[i][j] = (f4v){0.f,0.f,0.f,0.f};

  int nk = Kp >> 5;
  for(int kt=0; kt<nk; kt++){
    __syncthreads();
    {
      int c0 = tid, c1 = tid + 256;
      int r0 = c0>>2, k80 = c0&3;
      int r1 = c1>>2, k81 = c1&3;
      size_t ga0 = ((size_t)(b0r + (r0&3))*T_LEN + tb0 + (r0>>2))*Kp;
      size_t ga1 = ((size_t)(b0r + (r1&3))*T_LEN + tb0 + (r1>>2))*Kp;
      *(s8v*)&Al[r0][k80*8] = *(const s8v*)(A + ga0 + kt*32 + k80*8);
      *(s8v*)&Al[r1][k81*8] = *(const s8v*)(A + ga1 + kt*32 + k81*8);
      *(s8v*)&Bl[r0][k80*8] = *(const s8v*)(BT_ + (size_t)(nb+r0)*Kp + kt*32 + k80*8);
      *(s8v*)&Bl[r1][k81*8] = *(const s8v*)(BT_ + (size_t)(nb+r1)*Kp + kt*32 + k81*8);
    }
    __syncthreads();
    s8v af[4], bf[4];
    #pragma unroll
    for(int i=0;i<4;i++) af[i] = *(const s8v*)&Al[wm*64 + i*16 + lc][quad*8];
    #pragma unroll
    for(int j=0;j<4;j++) bf[j] = *(const s8v*)&Bl[wn*64 + j*16 + lc][quad*8];
    #pragma unroll
    for(int i=0;i<4;i++)
      #pragma unroll
      for(int j=0;j<4;j++)
        acc[i][j] = __builtin_amdgcn_mfma_f32_16x16x32_bf16(af[i], bf[j], acc[i][j],0,0,0);
  }

  // packed epilogue -> xq[dir][t][b][g][lc][ut], one u64 (4 ut) per (i,r)
  int dirq = (nb >= G3) ? 1 : 0;
  int c7b  = nb - dirq*G3 + wn*64;      // col within dir, minus lc and j*16
  int g    = c7b >> 8;
  int ut0  = (c7b >> 4) & 15;
  const float* bb = dirq ? biasB : biasA;
  float bj[4];
  #pragma unroll
  for(int j=0;j<4;j++){
    int cc = c7b + j*16 + lc;
    bj[j] = bb[cc] + ((g < 2) ? bb[G3 + cc] : 0.f);   // fold b[1] for z,r gates
  }
  #pragma unroll
  for(int i=0;i<4;i++){
    int t = tb0 + wm*16 + i*4 + quad;
    size_t base = ((((size_t)dirq*T_LEN + t)*B_SZ + b0r)*3 + g)*256 + lc*16 + ut0;
    #pragma unroll
    for(int r=0;r<4;r++){
      u16 p0 = f2bf(acc[i][0][r] + bj[0]);
      u16 p1 = f2bf(acc[i][1][r] + bj[1]);
      u16 p2 = f2bf(acc[i][2][r] + bj[2]);
      u16 p3 = f2bf(acc[i][3][r] + bj[3]);
      *(u64*)(Cq + base + (size_t)r*768) =
        (u64)p0 | ((u64)p1<<16) | ((u64)p2<<32) | ((u64)p3<<48);
    }
  }
}

// ---------------- GRU scan: fp8 K=128 MFMA, register-resident weights --------
// 32 blocks (dir x 16 batch-groups of 4) x 256 threads (4 waves, 1 wave/SIMD).
// Per wave: 192 N-cols (3 gates x 64 u) x K=256 fp8 -> 24 B-frags x 8 AGPRs =
// a0..a191. h exchanged per step via LDS as fp8 bytes; gate state in f32.
// 24 MFMAs/step/wave (12 N-tiles x 2 K-tiles of 16x16x128).

#define ACLB \
 "a0","a1","a2","a3","a4","a5","a6","a7","a8","a9","a10","a11","a12","a13","a14","a15", \
 "a16","a17","a18","a19","a20","a21","a22","a23","a24","a25","a26","a27","a28","a29","a30","a31", \
 "a32","a33","a34","a35","a36","a37","a38","a39","a40","a41","a42","a43","a44","a45","a46","a47", \
 "a48","a49","a50","a51","a52","a53","a54","a55","a56","a57","a58","a59","a60","a61","a62","a63", \
 "a64","a65","a66","a67","a68","a69","a70","a71","a72","a73","a74","a75","a76","a77","a78","a79", \
 "a80","a81","a82","a83","a84","a85","a86","a87","a88","a89","a90","a91","a92","a93","a94","a95", \
 "a96","a97","a98","a99","a100","a101","a102","a103","a104","a105","a106","a107","a108","a109","a110","a111", \
 "a112","a113","a114","a115","a116","a117","a118","a119","a120","a121","a122","a123","a124","a125","a126","a127", \
 "a128","a129","a130","a131","a132","a133","a134","a135","a136","a137","a138","a139","a140","a141","a142","a143", \
 "a144","a145","a146","a147","a148","a149","a150","a151","a152","a153","a154","a155","a156","a157","a158","a159", \
 "a160","a161","a162","a163","a164","a165","a166","a167","a168","a169","a170","a171","a172","a173","a174","a175", \
 "a176","a177","a178","a179","a180","a181","a182","a183","a184","a185","a186","a187","a188","a189","a190","a191"

#define AFENCE asm volatile("" ::: ACLB)

#define BINIT8(G,S,KT,A0,A1,A2,A3,A4,A5,A6,A7) { \
  const u8* p = rkd + ((size_t)((G)*256 + w*64 + (S)*16 + lc)<<8) + (KT)*128 + quad*32; \
  i4v t0 = *(const i4v*)p; \
  i4v t1 = *(const i4v*)(p+16); \
  asm volatile("v_accvgpr_write_b32 a" #A0 ", %0\n\t" \
               "v_accvgpr_write_b32 a" #A1 ", %1\n\t" \
               "v_accvgpr_write_b32 a" #A2 ", %2\n\t" \
               "v_accvgpr_write_b32 a" #A3 ", %3\n\t" \
               "v_accvgpr_write_b32 a" #A4 ", %4\n\t" \
               "v_accvgpr_write_b32 a" #A5 ", %5\n\t" \
               "v_accvgpr_write_b32 a" #A6 ", %6\n\t" \
               "v_accvgpr_write_b32 a" #A7 ", %7" \
               :: "v"(t0[0]),"v"(t0[1]),"v"(t0[2]),"v"(t0[3]), \
                  "v"(t1[0]),"v"(t1[1]),"v"(t1[2]),"v"(t1[3]) : ACLB); }

// fp8 K=128 MFMA, B from AGPR (cbsz/blgp default 0 = e4m3 both operands)
#define MFZ8(ACC,AF,AR) \
  asm("v_mfma_f32_16x16x128_f8f6f4 %0, %1, " AR ", 0" : "=&v"(ACC) : "v"(AF))
#define MFA8(ACC,AF,AR) \
  asm("v_mfma_f32_16x16x128_f8f6f4 %0, %1, " AR ", %0" : "+v"(ACC) : "v"(AF))

// MFMA->VALU hazard fence: orders all acc reads after 16 nop cycles
#define FENCE12 asm volatile("s_nop 7\n\ts_nop 7" \
  : "+v"(acc[0]),"+v"(acc[1]),"+v"(acc[2]),"+v"(acc[3]), \
    "+v"(acc[4]),"+v"(acc[5]),"+v"(acc[6]),"+v"(acc[7]), \
    "+v"(acc[8]),"+v"(acc[9]),"+v"(acc[10]),"+v"(acc[11]) :: ACLB)

#define LBAR asm volatile("s_waitcnt lgkmcnt(0)\n\ts_barrier" ::: ACLB, "memory")

__device__ __forceinline__ float bsel(u32x2 v, int i){
  u32 wv = (i & 2) ? (u32)v[1] : (u32)v[0];
  return __uint_as_float((i & 1) ? (wv & 0xffff0000u) : (wv << 16));
}

// gate + state update for one ut (cell = acc[.][0]; batch = quad)
#define GATE(UT) { \
  float xz = bsel(cz, UT); \
  float xr = bsel(cr, UT); \
  float xh = bsel(ch, UT); \
  float zf = acc[UT][0]   + xz; \
  float rf = acc[4+UT][0] + xr; \
  float rh = acc[8+UT][0] + b1h[UT]; \
  zf = __builtin_amdgcn_rcpf(1.f + __expf(-zf)); \
  rf = __builtin_amdgcn_rcpf(1.f + __expf(-rf)); \
  float hc = xh + rf*rh; \
  float e2 = __expf(2.f*hc); \
  float th = 1.f - 2.f*__builtin_amdgcn_rcpf(e2 + 1.f); \
  float hn = th + zf*(hpc[UT] - th); \
  hpc[UT] = hn; \
  u32 q8; asm("v_cvt_pk_fp8_f32 %0, %1, %2" : "=v"(q8) : "v"(hn), "v"(hn)); \
  hb8[nxt][quad*4][w*64 + (UT)*16 + lc] = (u8)(q8 & 0xffu); \
  if(MODE == 0) \
    hp[(UT)*16] = f2bf(hn); \
  else if(step == T_LEN-1) \
    h2out[(size_t)(b0+quad)*(2*U_DIM) + dir*U_DIM + w*64 + (UT)*16 + lc] = hn; \
}

template<int MODE>
__global__ __launch_bounds__(256,1) void gru_scan3(
    const u16* __restrict__ xq,    // packed preacts (see gemm_bt)
    const u8*  __restrict__ rkq,   // [2][768][256] fp8 transposed recurrent kernels
    const float* __restrict__ bF, const float* __restrict__ bB,  // b[2][768] f32
    u16* __restrict__ h1out,       // MODE 0: [BT,512]
    float* __restrict__ h2out)     // MODE 1: [64,512] final states
{
  int dir = blockIdx.x & 1, bg = blockIdx.x >> 1;
  int b0 = bg*4;
  int tid = threadIdx.x;
  int w = tid>>6, l = tid&63, lc = l&15, quad = l>>4;

  __shared__ u8 hb8[2][16][272];   // double-buffered h (fp8), rows {0,4,8,12} real
  for(int i=tid; i<2*16*272; i+=256) ((u8*)hb8)[i] = 0;

  const u8* rkd = rkq + (size_t)dir*G3*U_DIM;

  // B-frags: frag(g,s,kt) -> a[((g*4+s)*2+kt)*8 .. +7]
  BINIT8(0,0,0,  0,1,2,3,4,5,6,7)        BINIT8(0,0,1,  8,9,10,11,12,13,14,15)
  BINIT8(0,1,0, 16,17,18,19,20,21,22,23) BINIT8(0,1,1, 24,25,26,27,28,29,30,31)
  BINIT8(0,2,0, 32,33,34,35,36,37,38,39) BINIT8(0,2,1, 40,41,42,43,44,45,46,47)
  BINIT8(0,3,0, 48,49,50,51,52,53,54,55) BINIT8(0,3,1, 56,57,58,59,60,61,62,63)
  BINIT8(1,0,0, 64,65,66,67,68,69,70,71) BINIT8(1,0,1, 72,73,74,75,76,77,78,79)
  BINIT8(1,1,0, 80,81,82,83,84,85,86,87) BINIT8(1,1,1, 88,89,90,91,92,93,94,95)
  BINIT8(1,2,0, 96,97,98,99,100,101,102,103) BINIT8(1,2,1, 104,105,106,107,108,109,110,111)
  BINIT8(1,3,0, 112,113,114,115,116,117,118,119) BINIT8(1,3,1, 120,121,122,123,124,125,126,127)
  BINIT8(2,0,0, 128,129,130,131,132,133,134,135) BINIT8(2,0,1, 136,137,138,139,140,141,142,143)
  BINIT8(2,1,0, 144,145,146,147,148,149,150,151) BINIT8(2,1,1, 152,153,154,155,156,157,158,159)
  BINIT8(2,2,0, 160,161,162,163,164,165,166,167) BINIT8(2,2,1, 168,169,170,171,172,173,174,175)
  BINIT8(2,3,0, 176,177,178,179,180,181,182,183) BINIT8(2,3,1, 184,185,186,187,188,189,190,191)

  // recurrent bias for h-gate only (z,r folded into gemm bias)
  float b1h[4];
  const float* bias1 = (dir ? bB : bF) + G3;
  #pragma unroll
  for(int ut=0; ut<4; ut++) b1h[ut] = bias1[2*U_DIM + w*64 + ut*16 + lc];

  int t0 = dir ? (T_LEN-1) : 0;
  long qstride = dir ? -(long)(64*3*256) : (long)(64*3*256);
  const u16* xp = xq + ((((size_t)dir*T_LEN + t0)*B_SZ + (b0+quad))*3)*256 + lc*16 + w*4;
  long hstride = dir ? -(long)(2*U_DIM) : (long)(2*U_DIM);
  u16* hp = (MODE==0)
    ? (h1out + ((size_t)(b0+quad)*T_LEN + t0)*(2*U_DIM) + dir*U_DIM + w*64 + lc)
    : nullptr;

  float hpc[4] = {0.f, 0.f, 0.f, 0.f};   // carried h (own cells), f32

  __syncthreads();

  int cur = 0;
  for(int step=0; step<T_LEN; step++){
    AFENCE;
    int nxt = cur ^ 1;

    // packed xw preacts: 3 x 8B (4 ut cells each), hidden under the MFMA phase
    u32x2 cz = *(const u32x2*)(xp);
    u32x2 cr = *(const u32x2*)(xp + 256);
    u32x2 ch = *(const u32x2*)(xp + 512);

    // A-frags: h fp8, 32 B per lane per K-tile (row lc, k = quad*32..+31)
    i8v af0, af1;
    {
      const u8* p = &hb8[cur][lc][quad*32];
      i4v lo0 = *(const i4v*)p,        hi0 = *(const i4v*)(p+16);
      i4v lo1 = *(const i4v*)(p+128),  hi1 = *(const i4v*)(p+144);
      af0 = __builtin_shufflevector(lo0, hi0, 0,1,2,3,4,5,6,7);
      af1 = __builtin_shufflevector(lo1, hi1, 0,1,2,3,4,5,6,7);
    }

    f4v acc[12];   // [g*4+ut]; cell value in reg 0 (batch = quad at row quad*4)
    // K-tile 0
    MFZ8(acc[0], af0,"a[0:7]");     MFZ8(acc[1], af0,"a[16:23]");
    MFZ8(acc[2], af0,"a[32:39]");   MFZ8(acc[3], af0,"a[48:55]");
    MFZ8(acc[4], af0,"a[64:71]");   MFZ8(acc[5], af0,"a[80:87]");
    MFZ8(acc[6], af0,"a[96:103]");  MFZ8(acc[7], af0,"a[112:119]");
    MFZ8(acc[8], af0,"a[128:135]"); MFZ8(acc[9], af0,"a[144:151]");
    MFZ8(acc[10],af0,"a[160:167]"); MFZ8(acc[11],af0,"a[176:183]");
    // K-tile 1
    MFA8(acc[0], af1,"a[8:15]");    MFA8(acc[1], af1,"a[24:31]");
    MFA8(acc[2], af1,"a[40:47]");   MFA8(acc[3], af1,"a[56:63]");
    MFA8(acc[4], af1,"a[72:79]");   MFA8(acc[5], af1,"a[88:95]");
    MFA8(acc[6], af1,"a[104:111]"); MFA8(acc[7], af1,"a[120:127]");
    MFA8(acc[8], af1,"a[136:143]"); MFA8(acc[9], af1,"a[152:159]");
    MFA8(acc[10],af1,"a[168:175]"); MFA8(acc[11],af1,"a[184:191]");
    FENCE12;

    GATE(0)
    GATE(1)
    GATE(2)
    GATE(3)

    xp += qstride;
    if(MODE==0) hp += hstride;
    LBAR;
    cur ^= 1;
  }
}

// ---------------- final projection + softmax (f32 output) ---------------------
__global__ void out_softmax(const float* __restrict__ h2, const float* __restrict__ wout,
                            const float* __restrict__ bout, float* __restrict__ out)
{
  __shared__ float lg[C_DIM];
  int b = blockIdx.x, l = threadIdx.x;   // 64 threads = 1 wave
  float acc[C_DIM];
  #pragma unroll
  for(int c=0;c<C_DIM;c++) acc[c] = 0.f;
  for(int k=l; k<2*U_DIM; k+=64){
    float hv = h2[b*2*U_DIM + k];
    #pragma unroll
    for(int c=0;c<C_DIM;c++) acc[c] += hv * wout[k*C_DIM + c];
  }
  #pragma unroll
  for(int c=0;c<C_DIM;c++){
    float v = acc[c];
    for(int off=32; off; off>>=1) v += __shfl_down(v, off);
    if(l==0) lg[c] = v + bout[c];
  }
  __syncthreads();
  if(l==0){
    float mx = lg[0];
    for(int c=1;c<C_DIM;c++) mx = fmaxf(mx, lg[c]);
    float sum = 0.f, ex[C_DIM];
    for(int c=0;c<C_DIM;c++){ ex[c] = __expf(lg[c]-mx); sum += ex[c]; }
    for(int c=0;c<C_DIM;c++) out[b*C_DIM + c] = ex[c]/sum;
  }
}

extern "C" void kernel_launch(void* const* d_in, const int* in_sizes, int n_in,
                              void* d_out, int out_size, void* d_ws, size_t ws_size,
                              hipStream_t stream)
{
  const int*   x    = (const int*)d_in[0];
  const float* emb  = (const float*)d_in[1];
  const float* k1f  = (const float*)d_in[2];
  const float* rk1f = (const float*)d_in[3];
  const float* b1f  = (const float*)d_in[4];
  const float* k1b  = (const float*)d_in[5];
  const float* rk1b = (const float*)d_in[6];
  const float* b1b  = (const float*)d_in[7];
  const float* k2f  = (const float*)d_in[8];
  const float* rk2f = (const float*)d_in[9];
  const float* b2f  = (const float*)d_in[10];
  const float* k2b  = (const float*)d_in[11];
  const float* rk2b = (const float*)d_in[12];
  const float* b2b  = (const float*)d_in[13];
  const float* wout = (const float*)d_in[14];
  const float* bout = (const float*)d_in[15];

  char* ws = (char*)d_ws;
  u16*  k1t   = (u16*)(ws);                       // 983,040 B     [1536,320]
  u16*  k2t   = (u16*)(ws + 983040);              // 1,572,864 B   [1536,512]
  u8*   rkq   = (u8*)(ws + 2555904);              // 786,432 B     4x[768,256] fp8
  float* h2   = (float*)(ws + 4128768);           // 131,072 B     [64,512]
  u16*  h1    = (u16*)(ws + 4259840);             // 33,554,432 B  [BT,512]
  u16*  e_pad = (u16*)(ws + 4259840);             // (alias h1)
  u16*  xq    = (u16*)(ws + 37814272);            // 100,663,296 B packed preacts

  transpose_cc<<<(NTOT*EP +255)/256,256,0,stream>>>(k1f, k1b, k1t, E_DIM, EP, NTOT);
  transpose_cc<<<(NTOT*512+255)/256,256,0,stream>>>(k2f, k2b, k2t, 512, 512, NTOT);
  transpose_fp8<<<768,256,0,stream>>>(rk1f, rkq);
  transpose_fp8<<<768,256,0,stream>>>(rk1b, rkq + 1*G3*U_DIM);
  transpose_fp8<<<768,256,0,stream>>>(rk2f, rkq + 2*G3*U_DIM);
  transpose_fp8<<<768,256,0,stream>>>(rk2b, rkq + 3*G3*U_DIM);

  embed_pad<<<(BT*EP)/256,256,0,stream>>>(x, emb, e_pad);

  // layer 1: xq = pack(e @ K1 + b0 [+ b1 for z,r]) ; scan -> h1
  gemm_bt<<<dim3(12,256),256,0,stream>>>(e_pad, k1t, xq, EP, b1f, b1b);
  gru_scan3<0><<<32,256,0,stream>>>(xq, rkq, b1f, b1b, h1, nullptr);

  // layer 2: xq = pack(h1 @ K2 + b0 [+ b1 for z,r]) ; scan -> h2 (final states)
  gemm_bt<<<dim3(12,256),256,0,stream>>>(h1, k2t, xq, 512, b2f, b2b);
  gru_scan3<1><<<32,256,0,stream>>>(xq, rkq + 2*G3*U_DIM, b2f, b2b, nullptr, h2);

  out_softmax<<<64,64,0,stream>>>(h2, wout, bout, (float*)d_out);
}

// Round 6
// 1118.738 us; speedup vs baseline: 1.3206x; 1.0985x over previous
//
#include <hip/hip_runtime.h>

typedef unsigned char  u8;
typedef unsigned short u16;
typedef unsigned int   u32;
typedef unsigned long long u64;
typedef __attribute__((ext_vector_type(8))) short s8v;   // 8 x bf16 bits (4 VGPRs)
typedef __attribute__((ext_vector_type(4))) float f4v;   // MFMA accumulator
typedef __attribute__((ext_vector_type(4))) int   i4v;   // 4 VGPRs (generic 16B)
typedef __attribute__((ext_vector_type(8))) int   i8v;   // 8 VGPRs (fp8 MFMA operand)
typedef __attribute__((ext_vector_type(2))) unsigned int u32x2;

#define B_SZ  64
#define T_LEN 512
#define U_DIM 256
#define E_DIM 300
#define EP    320          // E padded to multiple of 32
#define G3    768          // 3*U
#define NTOT  1536         // both directions concatenated
#define C_DIM 20
#define BT    (B_SZ*T_LEN)

__device__ __forceinline__ float bf2f(u16 h){ return __uint_as_float(((u32)h)<<16); }
__device__ __forceinline__ u16 f2bf(float f){
  u32 u = __float_as_uint(f);
  u32 r = (u + 0x7FFFu + ((u>>16)&1u)) >> 16;   // RNE
  return (u16)r;
}

// f32 -> OCP e4m3fn, RNE, handles subnormals + 448 clamp (prep kernels only)
__device__ __forceinline__ u8 f2fp8(float f){
  u32 u = __float_as_uint(f);
  u32 s = (u>>24)&0x80u;
  u32 au = u & 0x7fffffffu;
  if(au < 0x3C800000u){                       // |f| < 2^-6: subnormal range
    float m = rintf(__uint_as_float(au) * 512.f);   // 0..8 (RNE)
    return (u8)(s | (u32)(int)m);             // m==8 -> 0x08 == 2^-6 normal
  }
  int e = (int)(au>>23) - 127;
  u32 mant = au & 0x7fffffu;
  u32 lsb = (mant>>20)&1u;
  mant += 0x7FFFFu + lsb;                     // RNE to 3 mantissa bits
  if(mant >> 23){ mant = 0; e += 1; }
  if(e > 8 || (e==8 && ((mant>>20)&7u)==7u)) return (u8)(s | 0x7Eu);  // clamp 448
  return (u8)(s | ((u32)(e+7)<<3) | ((mant>>20)&7u));
}

// ------------- embedding gather f32 -> bf16, K-pad (300 -> 320, zeros) --------
__global__ void embed_pad(const int* __restrict__ x, const float* __restrict__ emb,
                          u16* __restrict__ e){
  int idx = blockIdx.x*256 + threadIdx.x;
  if(idx >= BT*EP) return;
  int row = idx / EP, col = idx - row*EP;
  u16 v = 0;
  if(col < E_DIM) v = f2bf(emb[(size_t)x[row]*E_DIM + col]);
  e[idx] = v;
}

// ------ transpose + concat two f32 [K,768] sources -> bf16 dst[N][Kp] ---------
__global__ void transpose_cc(const float* __restrict__ A, const float* __restrict__ Bm,
                             u16* __restrict__ dst, int K, int Kp, int N){
  int idx = blockIdx.x*256 + threadIdx.x;
  if(idx >= N*Kp) return;
  int n = idx / Kp, k = idx - n*Kp;
  u16 v = 0;
  if(k < K){
    const float* s = (n < G3) ? A : Bm;
    int nn = (n < G3) ? n : n - G3;
    v = f2bf(s[(size_t)k*G3 + nn]);
  }
  dst[idx] = v;
}

// ------ recurrent kernel f32 [256][768] -> fp8 e4m3 transposed [768][256] -----
__global__ void transpose_fp8(const float* __restrict__ rk, u8* __restrict__ dst){
  int idx = blockIdx.x*256 + threadIdx.x;     // 768*256
  if(idx >= G3*U_DIM) return;
  int n = idx >> 8, k = idx & 255;
  dst[idx] = f2fp8(rk[(size_t)k*G3 + n]);
}

// ------- GEMM: packed preacts for the M=4 scan -------------------------------
// xq layout (u16): [dir][t][b][g][lc16][ut16]; total 2*512*64*3*256 u16.
// Recurrent bias b[1] for gates z,r (g<2) is folded in here (saves scan VALU).
__global__ __launch_bounds__(256) void gemm_bt(
    const u16* __restrict__ A, const u16* __restrict__ BT_, u16* __restrict__ Cq,
    int Kp, const float* __restrict__ biasA, const float* __restrict__ biasB)
{
  __shared__ u16 Al[128][40];   // +8 pad breaks bank collisions
  __shared__ u16 Bl[128][40];
  int tid = threadIdx.x;
  int w = tid>>6, l = tid&63, lc = l&15, quad = l>>4;
  int wm = w>>1, wn = w&1;
  int nb = blockIdx.x*128;
  int bg4 = blockIdx.y >> 4, tg = blockIdx.y & 15;
  int b0r = bg4*4, tb0 = tg*32;

  f4v acc[4][4];
  #pragma unroll
  for(int i=0;i<4;i++)
    #pragma unroll
    for(int j=0;j<4;j++) acc[i][j] = (f4v){0.f,0.f,0.f,0.f};

  int nk = Kp >> 5;
  for(int kt=0; kt<nk; kt++){
    __syncthreads();
    {
      int c0 = tid, c1 = tid + 256;
      int r0 = c0>>2, k80 = c0&3;
      int r1 = c1>>2, k81 = c1&3;
      size_t ga0 = ((size_t)(b0r + (r0&3))*T_LEN + tb0 + (r0>>2))*Kp;
      size_t ga1 = ((size_t)(b0r + (r1&3))*T_LEN + tb0 + (r1>>2))*Kp;
      *(s8v*)&Al[r0][k80*8] = *(const s8v*)(A + ga0 + kt*32 + k80*8);
      *(s8v*)&Al[r1][k81*8] = *(const s8v*)(A + ga1 + kt*32 + k81*8);
      *(s8v*)&Bl[r0][k80*8] = *(const s8v*)(BT_ + (size_t)(nb+r0)*Kp + kt*32 + k80*8);
      *(s8v*)&Bl[r1][k81*8] = *(const s8v*)(BT_ + (size_t)(nb+r1)*Kp + kt*32 + k81*8);
    }
    __syncthreads();
    s8v af[4], bf[4];
    #pragma unroll
    for(int i=0;i<4;i++) af[i] = *(const s8v*)&Al[wm*64 + i*16 + lc][quad*8];
    #pragma unroll
    for(int j=0;j<4;j++) bf[j] = *(const s8v*)&Bl[wn*64 + j*16 + lc][quad*8];
    #pragma unroll
    for(int i=0;i<4;i++)
      #pragma unroll
      for(int j=0;j<4;j++)
        acc[i][j] = __builtin_amdgcn_mfma_f32_16x16x32_bf16(af[i], bf[j], acc[i][j],0,0,0);
  }

  // packed epilogue -> xq[dir][t][b][g][lc][ut], one u64 (4 ut) per (i,r)
  int dirq = (nb >= G3) ? 1 : 0;
  int c7b  = nb - dirq*G3 + wn*64;      // col within dir, minus lc and j*16
  int g    = c7b >> 8;
  int ut0  = (c7b >> 4) & 15;
  const float* bb = dirq ? biasB : biasA;
  float bj[4];
  #pragma unroll
  for(int j=0;j<4;j++){
    int cc = c7b + j*16 + lc;
    bj[j] = bb[cc] + ((g < 2) ? bb[G3 + cc] : 0.f);   // fold b[1] for z,r gates
  }
  #pragma unroll
  for(int i=0;i<4;i++){
    int t = tb0 + wm*16 + i*4 + quad;
    size_t base = ((((size_t)dirq*T_LEN + t)*B_SZ + b0r)*3 + g)*256 + lc*16 + ut0;
    #pragma unroll
    for(int r=0;r<4;r++){
      u16 p0 = f2bf(acc[i][0][r] + bj[0]);
      u16 p1 = f2bf(acc[i][1][r] + bj[1]);
      u16 p2 = f2bf(acc[i][2][r] + bj[2]);
      u16 p3 = f2bf(acc[i][3][r] + bj[3]);
      *(u64*)(Cq + base + (size_t)r*768) =
        (u64)p0 | ((u64)p1<<16) | ((u64)p2<<32) | ((u64)p3<<48);
    }
  }
}

// ---------------- GRU scan: fp8 K=128 MFMA, register-resident weights --------
// 32 blocks (dir x 16 batch-groups of 4) x 256 threads (4 waves, 1 wave/SIMD).
// Per wave: 192 N-cols (3 gates x 64 u) x K=256 fp8 -> 24 B-frags x 8 AGPRs =
// a0..a191. h exchanged per step via LDS as fp8 bytes; gate state in f32.
// 24 MFMAs/step/wave (12 N-tiles x 2 K-tiles of 16x16x128).
// xq preact loads are software-pipelined one step ahead (HBM ~900cyc hidden).

#define ACLB \
 "a0","a1","a2","a3","a4","a5","a6","a7","a8","a9","a10","a11","a12","a13","a14","a15", \
 "a16","a17","a18","a19","a20","a21","a22","a23","a24","a25","a26","a27","a28","a29","a30","a31", \
 "a32","a33","a34","a35","a36","a37","a38","a39","a40","a41","a42","a43","a44","a45","a46","a47", \
 "a48","a49","a50","a51","a52","a53","a54","a55","a56","a57","a58","a59","a60","a61","a62","a63", \
 "a64","a65","a66","a67","a68","a69","a70","a71","a72","a73","a74","a75","a76","a77","a78","a79", \
 "a80","a81","a82","a83","a84","a85","a86","a87","a88","a89","a90","a91","a92","a93","a94","a95", \
 "a96","a97","a98","a99","a100","a101","a102","a103","a104","a105","a106","a107","a108","a109","a110","a111", \
 "a112","a113","a114","a115","a116","a117","a118","a119","a120","a121","a122","a123","a124","a125","a126","a127", \
 "a128","a129","a130","a131","a132","a133","a134","a135","a136","a137","a138","a139","a140","a141","a142","a143", \
 "a144","a145","a146","a147","a148","a149","a150","a151","a152","a153","a154","a155","a156","a157","a158","a159", \
 "a160","a161","a162","a163","a164","a165","a166","a167","a168","a169","a170","a171","a172","a173","a174","a175", \
 "a176","a177","a178","a179","a180","a181","a182","a183","a184","a185","a186","a187","a188","a189","a190","a191"

#define AFENCE asm volatile("" ::: ACLB)

#define BINIT8(G,S,KT,A0,A1,A2,A3,A4,A5,A6,A7) { \
  const u8* p = rkd + ((size_t)((G)*256 + w*64 + (S)*16 + lc)<<8) + (KT)*128 + quad*32; \
  i4v t0 = *(const i4v*)p; \
  i4v t1 = *(const i4v*)(p+16); \
  asm volatile("v_accvgpr_write_b32 a" #A0 ", %0\n\t" \
               "v_accvgpr_write_b32 a" #A1 ", %1\n\t" \
               "v_accvgpr_write_b32 a" #A2 ", %2\n\t" \
               "v_accvgpr_write_b32 a" #A3 ", %3\n\t" \
               "v_accvgpr_write_b32 a" #A4 ", %4\n\t" \
               "v_accvgpr_write_b32 a" #A5 ", %5\n\t" \
               "v_accvgpr_write_b32 a" #A6 ", %6\n\t" \
               "v_accvgpr_write_b32 a" #A7 ", %7" \
               :: "v"(t0[0]),"v"(t0[1]),"v"(t0[2]),"v"(t0[3]), \
                  "v"(t1[0]),"v"(t1[1]),"v"(t1[2]),"v"(t1[3]) : ACLB); }

// fp8 K=128 MFMA, B from AGPR (cbsz/blgp default 0 = e4m3 both operands)
#define MFZ8(ACC,AF,AR) \
  asm("v_mfma_f32_16x16x128_f8f6f4 %0, %1, " AR ", 0" : "=&v"(ACC) : "v"(AF))
#define MFA8(ACC,AF,AR) \
  asm("v_mfma_f32_16x16x128_f8f6f4 %0, %1, " AR ", %0" : "+v"(ACC) : "v"(AF))

// MFMA->VALU hazard fence: orders all acc reads after 16 nop cycles
#define FENCE12 asm volatile("s_nop 7\n\ts_nop 7" \
  : "+v"(acc[0]),"+v"(acc[1]),"+v"(acc[2]),"+v"(acc[3]), \
    "+v"(acc[4]),"+v"(acc[5]),"+v"(acc[6]),"+v"(acc[7]), \
    "+v"(acc[8]),"+v"(acc[9]),"+v"(acc[10]),"+v"(acc[11]) :: ACLB)

#define LBAR asm volatile("s_waitcnt lgkmcnt(0)\n\ts_barrier" ::: ACLB, "memory")

__device__ __forceinline__ float bsel(u32x2 v, int i){
  u32 wv = (i & 2) ? (u32)v[1] : (u32)v[0];
  return __uint_as_float((i & 1) ? (wv & 0xffff0000u) : (wv << 16));
}

// gate + state update for one ut (cell = acc[.][0]; batch = quad)
#define GATE(UT) { \
  float xz = bsel(cz, UT); \
  float xr = bsel(cr, UT); \
  float xh = bsel(ch, UT); \
  float zf = acc[UT][0]   + xz; \
  float rf = acc[4+UT][0] + xr; \
  float rh = acc[8+UT][0] + b1h[UT]; \
  zf = __builtin_amdgcn_rcpf(1.f + __expf(-zf)); \
  rf = __builtin_amdgcn_rcpf(1.f + __expf(-rf)); \
  float hc = xh + rf*rh; \
  float e2 = __expf(2.f*hc); \
  float th = 1.f - 2.f*__builtin_amdgcn_rcpf(e2 + 1.f); \
  float hn = th + zf*(hpc[UT] - th); \
  hpc[UT] = hn; \
  u32 q8; asm("v_cvt_pk_fp8_f32 %0, %1, %2" : "=v"(q8) : "v"(hn), "v"(hn)); \
  hb8[nxt][quad*4][w*64 + (UT)*16 + lc] = (u8)(q8 & 0xffu); \
  if(MODE == 0) \
    hp[(UT)*16] = f2bf(hn); \
  else if(step == T_LEN-1) \
    h2out[(size_t)(b0+quad)*(2*U_DIM) + dir*U_DIM + w*64 + (UT)*16 + lc] = hn; \
}

template<int MODE>
__global__ __launch_bounds__(256,1) void gru_scan3(
    const u16* __restrict__ xq,    // packed preacts (see gemm_bt)
    const u8*  __restrict__ rkq,   // [2][768][256] fp8 transposed recurrent kernels
    const float* __restrict__ bF, const float* __restrict__ bB,  // b[2][768] f32
    u16* __restrict__ h1out,       // MODE 0: [BT,512]
    float* __restrict__ h2out)     // MODE 1: [64,512] final states
{
  int dir = blockIdx.x & 1, bg = blockIdx.x >> 1;
  int b0 = bg*4;
  int tid = threadIdx.x;
  int w = tid>>6, l = tid&63, lc = l&15, quad = l>>4;

  __shared__ u8 hb8[2][16][272];   // double-buffered h (fp8), rows {0,4,8,12} real
  for(int i=tid; i<2*16*272; i+=256) ((u8*)hb8)[i] = 0;

  const u8* rkd = rkq + (size_t)dir*G3*U_DIM;

  // B-frags: frag(g,s,kt) -> a[((g*4+s)*2+kt)*8 .. +7]
  BINIT8(0,0,0,  0,1,2,3,4,5,6,7)        BINIT8(0,0,1,  8,9,10,11,12,13,14,15)
  BINIT8(0,1,0, 16,17,18,19,20,21,22,23) BINIT8(0,1,1, 24,25,26,27,28,29,30,31)
  BINIT8(0,2,0, 32,33,34,35,36,37,38,39) BINIT8(0,2,1, 40,41,42,43,44,45,46,47)
  BINIT8(0,3,0, 48,49,50,51,52,53,54,55) BINIT8(0,3,1, 56,57,58,59,60,61,62,63)
  BINIT8(1,0,0, 64,65,66,67,68,69,70,71) BINIT8(1,0,1, 72,73,74,75,76,77,78,79)
  BINIT8(1,1,0, 80,81,82,83,84,85,86,87) BINIT8(1,1,1, 88,89,90,91,92,93,94,95)
  BINIT8(1,2,0, 96,97,98,99,100,101,102,103) BINIT8(1,2,1, 104,105,106,107,108,109,110,111)
  BINIT8(1,3,0, 112,113,114,115,116,117,118,119) BINIT8(1,3,1, 120,121,122,123,124,125,126,127)
  BINIT8(2,0,0, 128,129,130,131,132,133,134,135) BINIT8(2,0,1, 136,137,138,139,140,141,142,143)
  BINIT8(2,1,0, 144,145,146,147,148,149,150,151) BINIT8(2,1,1, 152,153,154,155,156,157,158,159)
  BINIT8(2,2,0, 160,161,162,163,164,165,166,167) BINIT8(2,2,1, 168,169,170,171,172,173,174,175)
  BINIT8(2,3,0, 176,177,178,179,180,181,182,183) BINIT8(2,3,1, 184,185,186,187,188,189,190,191)

  // recurrent bias for h-gate only (z,r folded into gemm bias)
  float b1h[4];
  const float* bias1 = (dir ? bB : bF) + G3;
  #pragma unroll
  for(int ut=0; ut<4; ut++) b1h[ut] = bias1[2*U_DIM + w*64 + ut*16 + lc];

  int t0 = dir ? (T_LEN-1) : 0;
  long qstride = dir ? -(long)(64*3*256) : (long)(64*3*256);
  const u16* xp = xq + ((((size_t)dir*T_LEN + t0)*B_SZ + (b0+quad))*3)*256 + lc*16 + w*4;
  long hstride = dir ? -(long)(2*U_DIM) : (long)(2*U_DIM);
  u16* hp = (MODE==0)
    ? (h1out + ((size_t)(b0+quad)*T_LEN + t0)*(2*U_DIM) + dir*U_DIM + w*64 + lc)
    : nullptr;

  float hpc[4] = {0.f, 0.f, 0.f, 0.f};   // carried h (own cells), f32

  // prologue load for step 0 (pipelined: consumed this step, next prefetched)
  u32x2 cz = *(const u32x2*)(xp);
  u32x2 cr = *(const u32x2*)(xp + 256);
  u32x2 ch = *(const u32x2*)(xp + 512);

  __syncthreads();

  int cur = 0;
  for(int step=0; step<T_LEN; step++){
    AFENCE;
    int nxt = cur ^ 1;

    // A-frags: h fp8, 32 B per lane per K-tile (row lc, k = quad*32..+31)
    i8v af0, af1;
    {
      const u8* p = &hb8[cur][lc][quad*32];
      i4v lo0 = *(const i4v*)p,        hi0 = *(const i4v*)(p+16);
      i4v lo1 = *(const i4v*)(p+128),  hi1 = *(const i4v*)(p+144);
      af0 = __builtin_shufflevector(lo0, hi0, 0,1,2,3,4,5,6,7);
      af1 = __builtin_shufflevector(lo1, hi1, 0,1,2,3,4,5,6,7);
    }

    // prefetch next step's preacts (t=±512 lands in the other dir's region:
    // valid memory, values unused) — ~1 full step of latency cover
    const u16* xpn = xp + qstride;
    u32x2 czn = *(const u32x2*)(xpn);
    u32x2 crn = *(const u32x2*)(xpn + 256);
    u32x2 chn = *(const u32x2*)(xpn + 512);

    f4v acc[12];   // [g*4+ut]; cell value in reg 0 (batch = quad at row quad*4)
    // K-tile 0
    MFZ8(acc[0], af0,"a[0:7]");     MFZ8(acc[1], af0,"a[16:23]");
    MFZ8(acc[2], af0,"a[32:39]");   MFZ8(acc[3], af0,"a[48:55]");
    MFZ8(acc[4], af0,"a[64:71]");   MFZ8(acc[5], af0,"a[80:87]");
    MFZ8(acc[6], af0,"a[96:103]");  MFZ8(acc[7], af0,"a[112:119]");
    MFZ8(acc[8], af0,"a[128:135]"); MFZ8(acc[9], af0,"a[144:151]");
    MFZ8(acc[10],af0,"a[160:167]"); MFZ8(acc[11],af0,"a[176:183]");
    // K-tile 1
    MFA8(acc[0], af1,"a[8:15]");    MFA8(acc[1], af1,"a[24:31]");
    MFA8(acc[2], af1,"a[40:47]");   MFA8(acc[3], af1,"a[56:63]");
    MFA8(acc[4], af1,"a[72:79]");   MFA8(acc[5], af1,"a[88:95]");
    MFA8(acc[6], af1,"a[104:111]"); MFA8(acc[7], af1,"a[120:127]");
    MFA8(acc[8], af1,"a[136:143]"); MFA8(acc[9], af1,"a[152:159]");
    MFA8(acc[10],af1,"a[168:175]"); MFA8(acc[11],af1,"a[184:191]");
    FENCE12;

    GATE(0)
    GATE(1)
    GATE(2)
    GATE(3)

    cz = czn; cr = crn; ch = chn;
    xp = xpn;
    if(MODE==0) hp += hstride;
    LBAR;
    cur ^= 1;
  }
}

// ---------------- final projection + softmax (f32 output) ---------------------
__global__ void out_softmax(const float* __restrict__ h2, const float* __restrict__ wout,
                            const float* __restrict__ bout, float* __restrict__ out)
{
  __shared__ float lg[C_DIM];
  int b = blockIdx.x, l = threadIdx.x;   // 64 threads = 1 wave
  float acc[C_DIM];
  #pragma unroll
  for(int c=0;c<C_DIM;c++) acc[c] = 0.f;
  for(int k=l; k<2*U_DIM; k+=64){
    float hv = h2[b*2*U_DIM + k];
    #pragma unroll
    for(int c=0;c<C_DIM;c++) acc[c] += hv * wout[k*C_DIM + c];
  }
  #pragma unroll
  for(int c=0;c<C_DIM;c++){
    float v = acc[c];
    for(int off=32; off; off>>=1) v += __shfl_down(v, off);
    if(l==0) lg[c] = v + bout[c];
  }
  __syncthreads();
  if(l==0){
    float mx = lg[0];
    for(int c=1;c<C_DIM;c++) mx = fmaxf(mx, lg[c]);
    float sum = 0.f, ex[C_DIM];
    for(int c=0;c<C_DIM;c++){ ex[c] = __expf(lg[c]-mx); sum += ex[c]; }
    for(int c=0;c<C_DIM;c++) out[b*C_DIM + c] = ex[c]/sum;
  }
}

extern "C" void kernel_launch(void* const* d_in, const int* in_sizes, int n_in,
                              void* d_out, int out_size, void* d_ws, size_t ws_size,
                              hipStream_t stream)
{
  const int*   x    = (const int*)d_in[0];
  const float* emb  = (const float*)d_in[1];
  const float* k1f  = (const float*)d_in[2];
  const float* rk1f = (const float*)d_in[3];
  const float* b1f  = (const float*)d_in[4];
  const float* k1b  = (const float*)d_in[5];
  const float* rk1b = (const float*)d_in[6];
  const float* b1b  = (const float*)d_in[7];
  const float* k2f  = (const float*)d_in[8];
  const float* rk2f = (const float*)d_in[9];
  const float* b2f  = (const float*)d_in[10];
  const float* k2b  = (const float*)d_in[11];
  const float* rk2b = (const float*)d_in[12];
  const float* b2b  = (const float*)d_in[13];
  const float* wout = (const float*)d_in[14];
  const float* bout = (const float*)d_in[15];

  char* ws = (char*)d_ws;
  u16*  k1t   = (u16*)(ws);                       // 983,040 B     [1536,320]
  u16*  k2t   = (u16*)(ws + 983040);              // 1,572,864 B   [1536,512]
  u8*   rkq   = (u8*)(ws + 2555904);              // 786,432 B     4x[768,256] fp8
  float* h2   = (float*)(ws + 4128768);           // 131,072 B     [64,512]
  u16*  h1    = (u16*)(ws + 4259840);             // 33,554,432 B  [BT,512]
  u16*  e_pad = (u16*)(ws + 4259840);             // (alias h1)
  u16*  xq    = (u16*)(ws + 37814272);            // 100,663,296 B packed preacts

  transpose_cc<<<(NTOT*EP +255)/256,256,0,stream>>>(k1f, k1b, k1t, E_DIM, EP, NTOT);
  transpose_cc<<<(NTOT*512+255)/256,256,0,stream>>>(k2f, k2b, k2t, 512, 512, NTOT);
  transpose_fp8<<<768,256,0,stream>>>(rk1f, rkq);
  transpose_fp8<<<768,256,0,stream>>>(rk1b, rkq + 1*G3*U_DIM);
  transpose_fp8<<<768,256,0,stream>>>(rk2f, rkq + 2*G3*U_DIM);
  transpose_fp8<<<768,256,0,stream>>>(rk2b, rkq + 3*G3*U_DIM);

  embed_pad<<<(BT*EP)/256,256,0,stream>>>(x, emb, e_pad);

  // layer 1: xq = pack(e @ K1 + b0 [+ b1 for z,r]) ; scan -> h1
  gemm_bt<<<dim3(12,256),256,0,stream>>>(e_pad, k1t, xq, EP, b1f, b1b);
  gru_scan3<0><<<32,256,0,stream>>>(xq, rkq, b1f, b1b, h1, nullptr);

  // layer 2: xq = pack(h1 @ K2 + b0 [+ b1 for z,r]) ; scan -> h2 (final states)
  gemm_bt<<<dim3(12,256),256,0,stream>>>(h1, k2t, xq, 512, b2f, b2b);
  gru_scan3<1><<<32,256,0,stream>>>(xq, rkq + 2*G3*U_DIM, b2f, b2b, nullptr, h2);

  out_softmax<<<64,64,0,stream>>>(h2, wout, bout, (float*)d_out);
}